// Round 1
// baseline (277.398 us; speedup 1.0000x reference)
//
#include <hip/hip_runtime.h>
#include <hip/hip_bf16.h>

typedef __attribute__((ext_vector_type(8))) short short8;
typedef __attribute__((ext_vector_type(4))) float f32x4;

#define DEVI __device__ __forceinline__

static constexpr int NB = 4;
static constexpr int NN = 4096;
static constexpr int NE = 65536;
static constexpr int NF = 128;
static constexpr int MROWS = NB * NN; // 16384

DEVI short f2b(float f) {
    __hip_bfloat16 h = __float2bfloat16(f);
    return *reinterpret_cast<short*>(&h);
}

// ---------------- prep: fp32 -> bf16 weights ----------------
// order: [0]=W_src_gate [1]=W_dst_gate [2]=W_dst_update [3]=W_src_update [4]=W_edge_gate
__global__ void prep_weights(const float* __restrict__ w0, const float* __restrict__ w1,
                             const float* __restrict__ w2, const float* __restrict__ w3,
                             const float* __restrict__ w4, ushort* __restrict__ out) {
    int idx = blockIdx.x * 256 + threadIdx.x;   // 5*16384 total
    int wsel = idx >> 14;
    int off = idx & 16383;
    const float* src = wsel == 0 ? w0 : wsel == 1 ? w1 : wsel == 2 ? w2 : wsel == 3 ? w3 : w4;
    out[idx] = (ushort)f2b(src[off]);
}

// Stage one 128x128 bf16 weight into LDS, XOR-swizzled (byte ^= (n&7)<<4).
DEVI void stage_W(const ushort* __restrict__ Wg, ushort* Wl, int tid) {
    int n = tid >> 1;           // row 0..127
    int kh = (tid & 1) * 64;    // half-row in bf16 elems
#pragma unroll
    for (int c = 0; c < 8; ++c) {
        int k = kh + c * 8;
        short8 v = *reinterpret_cast<const short8*>(Wg + n * 128 + k);
        int byt = (n * 256 + k * 2) ^ ((n & 7) << 4);
        *reinterpret_cast<short8*>(reinterpret_cast<char*>(Wl) + byt) = v;
    }
}

// Compute a 64x128 = A[64x128] @ W^T tile. Wave wv owns rows wv*16..wv*16+15.
// A loaded directly from global fp32 (row-major, stride 128), converted to bf16.
// acc[nt][r]: row = wv*16 + (lane>>4)*4 + r, col = nt*16 + (lane&15).
DEVI void mfma_64x128(const float* __restrict__ Abase, const ushort* __restrict__ Wl,
                      int lane, int wv, f32x4 acc[8]) {
    const int colb = lane & 15;
    const int kgrp = lane >> 4;
    const int arow = wv * 16 + (lane & 15);
    short8 afrag[4];
#pragma unroll
    for (int ks = 0; ks < 4; ++ks) {
        int k0 = ks * 32 + kgrp * 8;
        const float* src = Abase + arow * 128 + k0;
        f32x4 lo = *reinterpret_cast<const f32x4*>(src);
        f32x4 hi = *reinterpret_cast<const f32x4*>(src + 4);
        short8 a;
#pragma unroll
        for (int q = 0; q < 4; ++q) a[q] = f2b(lo[q]);
#pragma unroll
        for (int q = 0; q < 4; ++q) a[4 + q] = f2b(hi[q]);
        afrag[ks] = a;
    }
#pragma unroll
    for (int nt = 0; nt < 8; ++nt) acc[nt] = f32x4{0.f, 0.f, 0.f, 0.f};
#pragma unroll
    for (int ks = 0; ks < 4; ++ks) {
#pragma unroll
        for (int nt = 0; nt < 8; ++nt) {
            int n = nt * 16 + colb;
            int byt = (n * 256 + (ks * 32 + kgrp * 8) * 2) ^ ((n & 7) << 4);
            short8 bfrag = *reinterpret_cast<const short8*>(
                reinterpret_cast<const char*>(Wl) + byt);
            acc[nt] = __builtin_amdgcn_mfma_f32_16x16x32_bf16(afrag[ks], bfrag, acc[nt], 0, 0, 0);
        }
    }
}

// ---------------- node projections: P[w] = node_feats @ W[w]^T + b[w] ----------------
__global__ __launch_bounds__(256) void node_proj_kernel(
    const float* __restrict__ node_feats,  // [MROWS,128]
    const ushort* __restrict__ Wbf,        // [5][128][128] bf16
    const float* __restrict__ bias0, const float* __restrict__ bias1,
    const float* __restrict__ bias2, const float* __restrict__ bias3,
    float* __restrict__ P)                 // [4][MROWS][128]
{
    __shared__ ushort Wl[128 * 128];  // 32 KB
    const int widx = blockIdx.y;
    const int row0 = blockIdx.x * 64;
    const int tid = threadIdx.x;

    stage_W(Wbf + (size_t)widx * 16384, Wl, tid);
    __syncthreads();

    const int lane = tid & 63, wv = tid >> 6;
    f32x4 acc[8];
    mfma_64x128(node_feats + (size_t)row0 * 128, Wl, lane, wv, acc);

    const float* bias = widx == 0 ? bias0 : widx == 1 ? bias1 : widx == 2 ? bias2 : bias3;
    float* Po = P + (size_t)widx * MROWS * 128;
    const int colb = lane & 15, kgrp = lane >> 4;
#pragma unroll
    for (int r = 0; r < 4; ++r) {
        int row = row0 + wv * 16 + kgrp * 4 + r;
#pragma unroll
        for (int nt = 0; nt < 8; ++nt) {
            int col = nt * 16 + colb;
            Po[(size_t)row * 128 + col] = acc[nt][r] + bias[col];
        }
    }
}

// ---------------- fused edge kernel ----------------
__global__ __launch_bounds__(256) void edge_kernel(
    const float* __restrict__ edge_feats,  // [NB,NE,128]
    const int* __restrict__ iIdx, const int* __restrict__ jIdx,
    const ushort* __restrict__ Weg,        // [128][128] bf16 (edge gate)
    const float* __restrict__ b_eg,
    const float* __restrict__ Psg, const float* __restrict__ Pdg,
    const float* __restrict__ Pdu,
    float* __restrict__ Sh, float* __restrict__ S,  // [NB,NN,128]
    float* __restrict__ yOut)                        // [NB,NE,128]
{
    __shared__ ushort Wl[128 * 128];  // 32 KB
    const int b = blockIdx.y;
    const int e0 = blockIdx.x * 64;
    const int tid = threadIdx.x;

    stage_W(Weg, Wl, tid);
    __syncthreads();

    const int lane = tid & 63, wv = tid >> 6;
    const float* Abase = edge_feats + ((size_t)b * NE + e0) * 128;
    f32x4 acc[8];
    mfma_64x128(Abase, Wl, lane, wv, acc);

    const int colb = lane & 15, kgrp = lane >> 4;
    const size_t nodeBase = (size_t)b * NN * 128;
#pragma unroll
    for (int r = 0; r < 4; ++r) {
        int erow = wv * 16 + kgrp * 4 + r;
        int e = e0 + erow;
        int ie = iIdx[e], je = jIdx[e];
        const float* sg = Psg + nodeBase + (size_t)ie * 128;
        const float* dg = Pdg + nodeBase + (size_t)je * 128;
        const float* du = Pdu + nodeBase + (size_t)je * 128;
        float* shp = Sh + nodeBase + (size_t)ie * 128;
        float* sp = S + nodeBase + (size_t)ie * 128;
        const float* ef = Abase + (size_t)erow * 128;
        float* yo = yOut + ((size_t)b * NE + e) * 128;
#pragma unroll
        for (int nt = 0; nt < 8; ++nt) {
            int col = nt * 16 + colb;
            float y = acc[nt][r] + b_eg[col] + sg[col] + dg[col];
            float sig = 1.0f / (1.0f + __expf(-y));
            yo[col] = ef[col] + y * sig;              // edge residual + silu(y)
            atomicAdd(&shp[col], du[col] * sig);
            atomicAdd(&sp[col], sig);
        }
    }
}

// ---------------- node finalize ----------------
__global__ __launch_bounds__(256) void finalize_kernel(
    const float* __restrict__ nf, const float* __restrict__ Psu,
    const float* __restrict__ Sh, const float* __restrict__ S,
    float* __restrict__ xOut)
{
    int idx = blockIdx.x * 256 + threadIdx.x;  // per float4
    f32x4 a = reinterpret_cast<const f32x4*>(nf)[idx];
    f32x4 su = reinterpret_cast<const f32x4*>(Psu)[idx];
    f32x4 sh = reinterpret_cast<const f32x4*>(Sh)[idx];
    f32x4 s = reinterpret_cast<const f32x4*>(S)[idx];
    f32x4 r;
#pragma unroll
    for (int q = 0; q < 4; ++q) {
        float h = sh[q] / (s[q] + 1e-6f);
        float v = su[q] + h;
        r[q] = a[q] + v / (1.f + __expf(-v));  // residual + silu
    }
    reinterpret_cast<f32x4*>(xOut)[idx] = r;
}

extern "C" void kernel_launch(void* const* d_in, const int* in_sizes, int n_in,
                              void* d_out, int out_size, void* d_ws, size_t ws_size,
                              hipStream_t stream) {
    (void)in_sizes; (void)n_in; (void)out_size; (void)ws_size;

    const float* node_feats = (const float*)d_in[0];
    const float* edge_feats = (const float*)d_in[1];
    const int* iIdx = (const int*)d_in[2];
    const int* jIdx = (const int*)d_in[3];
    const float* Wsg = (const float*)d_in[4];  const float* bsg = (const float*)d_in[5];
    const float* Wdg = (const float*)d_in[6];  const float* bdg = (const float*)d_in[7];
    const float* Weg = (const float*)d_in[8];  const float* beg = (const float*)d_in[9];
    const float* Wsu = (const float*)d_in[10]; const float* bsu = (const float*)d_in[11];
    const float* Wdu = (const float*)d_in[12]; const float* bdu = (const float*)d_in[13];

    float* out = (float*)d_out;
    float* xOut = out;                               // [NB,NN,128]
    float* yOut = out + (size_t)MROWS * 128;         // [NB,NE,128]

    // workspace layout (floats)
    float* P = (float*)d_ws;                          // [4][MROWS][128]
    float* Sh = P + (size_t)4 * MROWS * 128;          // [MROWS][128]
    float* S = Sh + (size_t)MROWS * 128;              // [MROWS][128]
    ushort* Wbf = (ushort*)(S + (size_t)MROWS * 128); // [5][128][128] bf16

    hipMemsetAsync(Sh, 0, (size_t)2 * MROWS * 128 * sizeof(float), stream);

    prep_weights<<<(5 * 16384) / 256, 256, 0, stream>>>(Wsg, Wdg, Wdu, Wsu, Weg, Wbf);

    dim3 gA(MROWS / 64, 4);
    node_proj_kernel<<<gA, 256, 0, stream>>>(node_feats, Wbf, bsg, bdg, bdu, bsu, P);

    dim3 gB(NE / 64, NB);
    edge_kernel<<<gB, 256, 0, stream>>>(edge_feats, iIdx, jIdx, Wbf + (size_t)4 * 16384, beg,
                                        P,                                  // src_gate
                                        P + (size_t)1 * MROWS * 128,        // dst_gate
                                        P + (size_t)2 * MROWS * 128,        // dst_update
                                        Sh, S, yOut);

    finalize_kernel<<<(MROWS * 128 / 4) / 256, 256, 0, stream>>>(
        node_feats, P + (size_t)3 * MROWS * 128, Sh, S, xOut);
}

// Round 2
// 200.703 us; speedup vs baseline: 1.3821x; 1.3821x over previous
//
#include <hip/hip_runtime.h>
#include <hip/hip_bf16.h>

typedef __attribute__((ext_vector_type(8))) short short8;
typedef __attribute__((ext_vector_type(4))) float f32x4;
typedef __attribute__((ext_vector_type(2))) float f32x2;

#define DEVI __device__ __forceinline__

static constexpr int NB = 4;
static constexpr int NN = 4096;
static constexpr int NE = 65536;
static constexpr int MROWS = NB * NN; // 16384

DEVI short f2b(float f) {
    __hip_bfloat16 h = __float2bfloat16(f);
    return *reinterpret_cast<short*>(&h);
}
DEVI float b2f(ushort u) {
    uint v = (uint)u << 16;
    float f;
    __builtin_memcpy(&f, &v, 4);
    return f;
}

// ---------------- prep: fp32 -> bf16 weights ----------------
// order: [0]=W_src_gate [1]=W_dst_gate [2]=W_dst_update [3]=W_src_update [4]=W_edge_gate
__global__ void prep_weights(const float* __restrict__ w0, const float* __restrict__ w1,
                             const float* __restrict__ w2, const float* __restrict__ w3,
                             const float* __restrict__ w4, ushort* __restrict__ out) {
    int idx = blockIdx.x * 256 + threadIdx.x;   // 5*16384 total
    int wsel = idx >> 14;
    int off = idx & 16383;
    const float* src = wsel == 0 ? w0 : wsel == 1 ? w1 : wsel == 2 ? w2 : wsel == 3 ? w3 : w4;
    out[idx] = (ushort)f2b(src[off]);
}

// ---------------- counting sort of edges by destination i ----------------
__global__ void hist_kernel(const int* __restrict__ iIdx, int* __restrict__ cnt) {
    int e = blockIdx.x * 256 + threadIdx.x;
    atomicAdd(&cnt[iIdx[e]], 1);
}

__global__ __launch_bounds__(256) void scan_kernel(const int* __restrict__ cnt,
                                                   int* __restrict__ start) {
    __shared__ int ls[256];
    int t = threadIdx.x;
    int base = t * 16;
    int loc[16];
    int s = 0;
#pragma unroll
    for (int q = 0; q < 16; ++q) { loc[q] = s; s += cnt[base + q]; }
    ls[t] = s;
    __syncthreads();
    for (int off = 1; off < 256; off <<= 1) {
        int v = (t >= off) ? ls[t - off] : 0;
        __syncthreads();
        ls[t] += v;
        __syncthreads();
    }
    int ex = ls[t] - s;   // exclusive prefix of this thread's chunk
#pragma unroll
    for (int q = 0; q < 16; ++q) start[base + q] = ex + loc[q];
    if (t == 255) start[4096] = ex + s;
}

__global__ void scatter_kernel(const int* __restrict__ iIdx, const int* __restrict__ start,
                               int* __restrict__ cur, int* __restrict__ perm) {
    int e = blockIdx.x * 256 + threadIdx.x;
    int b = iIdx[e];
    int pos = start[b] + atomicAdd(&cur[b], 1);
    perm[pos] = e;
}

// Stage one 128x128 bf16 weight into LDS, XOR-swizzled (byte ^= (n&7)<<4).
DEVI void stage_W(const ushort* __restrict__ Wg, ushort* Wl, int tid) {
    int n = tid >> 1;           // row 0..127
    int kh = (tid & 1) * 64;    // half-row in bf16 elems
#pragma unroll
    for (int c = 0; c < 8; ++c) {
        int k = kh + c * 8;
        short8 v = *reinterpret_cast<const short8*>(Wg + n * 128 + k);
        int byt = (n * 256 + k * 2) ^ ((n & 7) << 4);
        *reinterpret_cast<short8*>(reinterpret_cast<char*>(Wl) + byt) = v;
    }
}

// Compute a 64x128 = A[64x128] @ W^T tile. Wave wv owns rows wv*16..wv*16+15.
// acc[nt][r]: row = wv*16 + (lane>>4)*4 + r, col = nt*16 + (lane&15).
DEVI void mfma_64x128(const float* __restrict__ Abase, const ushort* __restrict__ Wl,
                      int lane, int wv, f32x4 acc[8]) {
    const int colb = lane & 15;
    const int kgrp = lane >> 4;
    const int arow = wv * 16 + (lane & 15);
    short8 afrag[4];
#pragma unroll
    for (int ks = 0; ks < 4; ++ks) {
        int k0 = ks * 32 + kgrp * 8;
        const float* src = Abase + arow * 128 + k0;
        f32x4 lo = *reinterpret_cast<const f32x4*>(src);
        f32x4 hi = *reinterpret_cast<const f32x4*>(src + 4);
        short8 a;
#pragma unroll
        for (int q = 0; q < 4; ++q) a[q] = f2b(lo[q]);
#pragma unroll
        for (int q = 0; q < 4; ++q) a[4 + q] = f2b(hi[q]);
        afrag[ks] = a;
    }
#pragma unroll
    for (int nt = 0; nt < 8; ++nt) acc[nt] = f32x4{0.f, 0.f, 0.f, 0.f};
#pragma unroll
    for (int ks = 0; ks < 4; ++ks) {
#pragma unroll
        for (int nt = 0; nt < 8; ++nt) {
            int n = nt * 16 + colb;
            int byt = (n * 256 + (ks * 32 + kgrp * 8) * 2) ^ ((n & 7) << 4);
            short8 bfrag = *reinterpret_cast<const short8*>(
                reinterpret_cast<const char*>(Wl) + byt);
            acc[nt] = __builtin_amdgcn_mfma_f32_16x16x32_bf16(afrag[ks], bfrag, acc[nt], 0, 0, 0);
        }
    }
}

// ---------------- node projections: P[w] = bf16(node_feats @ W[w]^T + b[w]) ----------------
__global__ __launch_bounds__(256) void node_proj_kernel(
    const float* __restrict__ node_feats,  // [MROWS,128]
    const ushort* __restrict__ Wbf,        // [5][128][128] bf16
    const float* __restrict__ bias0, const float* __restrict__ bias1,
    const float* __restrict__ bias2, const float* __restrict__ bias3,
    ushort* __restrict__ P)                // [4][MROWS][128] bf16
{
    __shared__ ushort Wl[128 * 128];  // 32 KB
    const int widx = blockIdx.y;
    const int row0 = blockIdx.x * 64;
    const int tid = threadIdx.x;

    stage_W(Wbf + (size_t)widx * 16384, Wl, tid);
    __syncthreads();

    const int lane = tid & 63, wv = tid >> 6;
    f32x4 acc[8];
    mfma_64x128(node_feats + (size_t)row0 * 128, Wl, lane, wv, acc);

    const float* bias = widx == 0 ? bias0 : widx == 1 ? bias1 : widx == 2 ? bias2 : bias3;
    ushort* Po = P + (size_t)widx * MROWS * 128;
    const int colb = lane & 15, kgrp = lane >> 4;
#pragma unroll
    for (int r = 0; r < 4; ++r) {
        int row = row0 + wv * 16 + kgrp * 4 + r;
#pragma unroll
        for (int nt = 0; nt < 8; ++nt) {
            int col = nt * 16 + colb;
            Po[(size_t)row * 128 + col] = (ushort)f2b(acc[nt][r] + bias[col]);
        }
    }
}

// ---------------- fused edge kernel (no atomics) ----------------
__global__ __launch_bounds__(256) void edge_kernel(
    const float* __restrict__ edge_feats,  // [NB,NE,128]
    const int* __restrict__ iIdx, const int* __restrict__ jIdx,
    const ushort* __restrict__ Weg,        // [128][128] bf16 (edge gate)
    const float* __restrict__ b_eg,
    const ushort* __restrict__ Psg, const ushort* __restrict__ Pdg,
    ushort* __restrict__ sigOut,           // [NB,NE,128] bf16
    float* __restrict__ yOut)              // [NB,NE,128]
{
    __shared__ ushort Wl[128 * 128];  // 32 KB
    const int b = blockIdx.y;
    const int e0 = blockIdx.x * 64;
    const int tid = threadIdx.x;

    stage_W(Weg, Wl, tid);
    __syncthreads();

    const int lane = tid & 63, wv = tid >> 6;
    const float* Abase = edge_feats + ((size_t)b * NE + e0) * 128;
    f32x4 acc[8];
    mfma_64x128(Abase, Wl, lane, wv, acc);

    const int colb = lane & 15, kgrp = lane >> 4;
    const size_t nodeBase = (size_t)b * NN * 128;
#pragma unroll
    for (int r = 0; r < 4; ++r) {
        int erow = wv * 16 + kgrp * 4 + r;
        int e = e0 + erow;
        int ie = iIdx[e], je = jIdx[e];
        const ushort* sg = Psg + nodeBase + (size_t)ie * 128;
        const ushort* dg = Pdg + nodeBase + (size_t)je * 128;
        const float* ef = Abase + (size_t)erow * 128;
        float* yo = yOut + ((size_t)b * NE + e) * 128;
        ushort* so = sigOut + ((size_t)b * NE + e) * 128;
#pragma unroll
        for (int nt = 0; nt < 8; ++nt) {
            int col = nt * 16 + colb;
            float y = acc[nt][r] + b_eg[col] + b2f(sg[col]) + b2f(dg[col]);
            float sig = 1.0f / (1.0f + __expf(-y));
            yo[col] = ef[col] + y * sig;              // edge residual + silu(y)
            so[col] = (ushort)f2b(sig);
        }
    }
}

// ---------------- per-node CSR reduce + finalize ----------------
__global__ __launch_bounds__(256) void node_reduce_kernel(
    const ushort* __restrict__ sigma,   // [NB,NE,128] bf16
    const int* __restrict__ perm,       // [NE]
    const int* __restrict__ start,      // [NN+1]
    const int* __restrict__ jIdx,       // [NE]
    const ushort* __restrict__ Pdu,     // [MROWS,128] bf16
    const ushort* __restrict__ Psu,     // [MROWS,128] bf16
    const float* __restrict__ nf,       // [MROWS,128]
    float* __restrict__ xOut)           // [MROWS,128]
{
    int task = blockIdx.x * 4 + (threadIdx.x >> 6);  // 0..16383
    int lane = threadIdx.x & 63;
    int b = task >> 12;
    int n = task & 4095;
    int s0 = start[n], s1 = start[n + 1];

    const size_t ebase = (size_t)b * NE;
    const size_t nbase = (size_t)b * NN;

    float S0 = 0.f, S1 = 0.f, Sh0 = 0.f, Sh1 = 0.f;
    for (int k = s0; k < s1; ++k) {
        int e = perm[k];
        int j = jIdx[e];
        uint sg2 = *reinterpret_cast<const uint*>(sigma + (ebase + e) * 128 + lane * 2);
        uint du2 = *reinterpret_cast<const uint*>(Pdu + (nbase + j) * 128 + lane * 2);
        float sa = b2f((ushort)(sg2 & 0xffff));
        float sb = b2f((ushort)(sg2 >> 16));
        float da = b2f((ushort)(du2 & 0xffff));
        float db = b2f((ushort)(du2 >> 16));
        S0 += sa; S1 += sb;
        Sh0 += da * sa; Sh1 += db * sb;
    }

    size_t off = (nbase + n) * 128 + lane * 2;
    uint su2 = *reinterpret_cast<const uint*>(Psu + off);
    f32x2 a = *reinterpret_cast<const f32x2*>(nf + off);
    float h0 = Sh0 / (S0 + 1e-6f);
    float h1 = Sh1 / (S1 + 1e-6f);
    float v0 = b2f((ushort)(su2 & 0xffff)) + h0;
    float v1 = b2f((ushort)(su2 >> 16)) + h1;
    f32x2 r;
    r[0] = a[0] + v0 / (1.f + __expf(-v0));
    r[1] = a[1] + v1 / (1.f + __expf(-v1));
    *reinterpret_cast<f32x2*>(xOut + off) = r;
}

extern "C" void kernel_launch(void* const* d_in, const int* in_sizes, int n_in,
                              void* d_out, int out_size, void* d_ws, size_t ws_size,
                              hipStream_t stream) {
    (void)in_sizes; (void)n_in; (void)out_size; (void)ws_size;

    const float* node_feats = (const float*)d_in[0];
    const float* edge_feats = (const float*)d_in[1];
    const int* iIdx = (const int*)d_in[2];
    const int* jIdx = (const int*)d_in[3];
    const float* Wsg = (const float*)d_in[4];  const float* bsg = (const float*)d_in[5];
    const float* Wdg = (const float*)d_in[6];  const float* bdg = (const float*)d_in[7];
    const float* Weg = (const float*)d_in[8];  const float* beg = (const float*)d_in[9];
    const float* Wsu = (const float*)d_in[10]; const float* bsu = (const float*)d_in[11];
    const float* Wdu = (const float*)d_in[12]; const float* bdu = (const float*)d_in[13];

    float* out = (float*)d_out;
    float* xOut = out;                               // [NB,NN,128]
    float* yOut = out + (size_t)MROWS * 128;         // [NB,NE,128]

    // workspace layout
    ushort* sigma = (ushort*)d_ws;                            // [NB*NE*128] bf16 (67.1 MB)
    ushort* P = sigma + (size_t)NB * NE * 128;                // [4][MROWS][128] bf16 (16.8 MB)
    ushort* Wbf = P + (size_t)4 * MROWS * 128;                // [5][128][128] bf16 (160 KB)
    int* perm = (int*)(Wbf + 5 * 16384);                      // [NE]
    int* cnt = perm + NE;                                     // [4096]
    int* cur = cnt + 4096;                                    // [4096]
    int* start = cur + 4096;                                  // [4097]

    hipMemsetAsync(cnt, 0, 2 * 4096 * sizeof(int), stream);   // cnt + cur

    prep_weights<<<(5 * 16384) / 256, 256, 0, stream>>>(Wsg, Wdg, Wdu, Wsu, Weg, Wbf);

    hist_kernel<<<NE / 256, 256, 0, stream>>>(iIdx, cnt);
    scan_kernel<<<1, 256, 0, stream>>>(cnt, start);
    scatter_kernel<<<NE / 256, 256, 0, stream>>>(iIdx, start, cur, perm);

    dim3 gA(MROWS / 64, 4);
    node_proj_kernel<<<gA, 256, 0, stream>>>(node_feats, Wbf, bsg, bdg, bdu, bsu, P);

    dim3 gB(NE / 64, NB);
    edge_kernel<<<gB, 256, 0, stream>>>(edge_feats, iIdx, jIdx, Wbf + (size_t)4 * 16384, beg,
                                        P,                                  // src_gate
                                        P + (size_t)1 * MROWS * 128,        // dst_gate
                                        sigma, yOut);

    node_reduce_kernel<<<MROWS / 4, 256, 0, stream>>>(
        sigma, perm, start, jIdx,
        P + (size_t)2 * MROWS * 128,   // dst_update
        P + (size_t)3 * MROWS * 128,   // src_update
        node_feats, xOut);
}

// Round 4
// 198.312 us; speedup vs baseline: 1.3988x; 1.0121x over previous
//
#include <hip/hip_runtime.h>
#include <hip/hip_bf16.h>

typedef __attribute__((ext_vector_type(8))) short short8;
typedef __attribute__((ext_vector_type(4))) float f32x4;
typedef __attribute__((ext_vector_type(2))) float f32x2;

#define DEVI __device__ __forceinline__

static constexpr int NB = 4;
static constexpr int NN = 4096;
static constexpr int NE = 65536;
static constexpr int MROWS = NB * NN; // 16384

DEVI short f2b(float f) {
    __hip_bfloat16 h = __float2bfloat16(f);
    return *reinterpret_cast<short*>(&h);
}
DEVI float b2f(ushort u) {
    uint v = (uint)u << 16;
    float f;
    __builtin_memcpy(&f, &v, 4);
    return f;
}

// ---------------- prep: fp32 -> bf16 weights ----------------
// order: [0]=W_src_gate [1]=W_dst_gate [2]=W_dst_update [3]=W_src_update [4]=W_edge_gate
__global__ void prep_weights(const float* __restrict__ w0, const float* __restrict__ w1,
                             const float* __restrict__ w2, const float* __restrict__ w3,
                             const float* __restrict__ w4, ushort* __restrict__ out) {
    int idx = blockIdx.x * 256 + threadIdx.x;   // 5*16384 total
    int wsel = idx >> 14;
    int off = idx & 16383;
    const float* src = wsel == 0 ? w0 : wsel == 1 ? w1 : wsel == 2 ? w2 : wsel == 3 ? w3 : w4;
    out[idx] = (ushort)f2b(src[off]);
}

// ---------------- counting sort of edges by destination i ----------------
__global__ void hist_kernel(const int* __restrict__ iIdx, int* __restrict__ cnt) {
    int e = blockIdx.x * 256 + threadIdx.x;
    atomicAdd(&cnt[iIdx[e]], 1);
}

__global__ __launch_bounds__(256) void scan_kernel(const int* __restrict__ cnt,
                                                   int* __restrict__ start) {
    __shared__ int ls[256];
    int t = threadIdx.x;
    int base = t * 16;
    int loc[16];
    int s = 0;
#pragma unroll
    for (int q = 0; q < 16; ++q) { loc[q] = s; s += cnt[base + q]; }
    ls[t] = s;
    __syncthreads();
    for (int off = 1; off < 256; off <<= 1) {
        int v = (t >= off) ? ls[t - off] : 0;
        __syncthreads();
        ls[t] += v;
        __syncthreads();
    }
    int ex = ls[t] - s;   // exclusive prefix of this thread's chunk
#pragma unroll
    for (int q = 0; q < 16; ++q) start[base + q] = ex + loc[q];
    if (t == 255) start[4096] = ex + s;
}

__global__ void scatter_kernel(const int* __restrict__ iIdx, const int* __restrict__ start,
                               int* __restrict__ cur, int* __restrict__ perm) {
    int e = blockIdx.x * 256 + threadIdx.x;
    int b = iIdx[e];
    int pos = start[b] + atomicAdd(&cur[b], 1);
    perm[pos] = e;
}

// Stage one 128x128 bf16 weight into LDS, XOR-swizzled (byte ^= (n&7)<<4).
DEVI void stage_W(const ushort* __restrict__ Wg, ushort* Wl, int tid) {
    int n = tid >> 1;           // row 0..127
    int kh = (tid & 1) * 64;    // half-row in bf16 elems
#pragma unroll
    for (int c = 0; c < 8; ++c) {
        int k = kh + c * 8;
        short8 v = *reinterpret_cast<const short8*>(Wg + n * 128 + k);
        int byt = (n * 256 + k * 2) ^ ((n & 7) << 4);
        *reinterpret_cast<short8*>(reinterpret_cast<char*>(Wl) + byt) = v;
    }
}

// Load this lane's A fragments (K=128 split in 4 ks-slices) from a fp32 row.
DEVI void load_afrag(const float* __restrict__ rowptr, int kgrp, short8 afrag[4]) {
#pragma unroll
    for (int ks = 0; ks < 4; ++ks) {
        int k0 = ks * 32 + kgrp * 8;
        f32x4 lo = *reinterpret_cast<const f32x4*>(rowptr + k0);
        f32x4 hi = *reinterpret_cast<const f32x4*>(rowptr + k0 + 4);
        short8 a;
#pragma unroll
        for (int q = 0; q < 4; ++q) a[q] = f2b(lo[q]);
#pragma unroll
        for (int q = 0; q < 4; ++q) a[4 + q] = f2b(hi[q]);
        afrag[ks] = a;
    }
}

// acc[nt]: row = wv*16 + (lane>>4)*4 + r, col = nt*16 + (lane&15), for this wave's 16-row tile.
DEVI void mfma_frags(const short8 afrag[4], const ushort* __restrict__ Wl,
                     int lane, f32x4 acc[8]) {
    const int colb = lane & 15;
    const int kgrp = lane >> 4;
#pragma unroll
    for (int nt = 0; nt < 8; ++nt) acc[nt] = f32x4{0.f, 0.f, 0.f, 0.f};
#pragma unroll
    for (int ks = 0; ks < 4; ++ks) {
#pragma unroll
        for (int nt = 0; nt < 8; ++nt) {
            int n = nt * 16 + colb;
            int byt = (n * 256 + (ks * 32 + kgrp * 8) * 2) ^ ((n & 7) << 4);
            short8 bfrag = *reinterpret_cast<const short8*>(
                reinterpret_cast<const char*>(Wl) + byt);
            acc[nt] = __builtin_amdgcn_mfma_f32_16x16x32_bf16(afrag[ks], bfrag, acc[nt], 0, 0, 0);
        }
    }
}

// ---------------- node projections: P[w] = bf16(node_feats @ W[w]^T + b[w]) ----------------
__global__ __launch_bounds__(256) void node_proj_kernel(
    const float* __restrict__ node_feats,  // [MROWS,128]
    const ushort* __restrict__ Wbf,        // [5][128][128] bf16
    const float* __restrict__ bias0, const float* __restrict__ bias1,
    const float* __restrict__ bias2, const float* __restrict__ bias3,
    ushort* __restrict__ P)                // [4][MROWS][128] bf16
{
    __shared__ ushort Wl[128 * 128];  // 32 KB
    const int widx = blockIdx.y;
    const int row0 = blockIdx.x * 64;
    const int tid = threadIdx.x;

    stage_W(Wbf + (size_t)widx * 16384, Wl, tid);
    __syncthreads();

    const int lane = tid & 63, wv = tid >> 6;
    const int colb = lane & 15, kgrp = lane >> 4;
    short8 afrag[4];
    load_afrag(node_feats + (size_t)(row0 + wv * 16 + colb) * 128, kgrp, afrag);
    f32x4 acc[8];
    mfma_frags(afrag, Wl, lane, acc);

    const float* bias = widx == 0 ? bias0 : widx == 1 ? bias1 : widx == 2 ? bias2 : bias3;
    ushort* Po = P + (size_t)widx * MROWS * 128;
#pragma unroll
    for (int r = 0; r < 4; ++r) {
        int row = row0 + wv * 16 + kgrp * 4 + r;
#pragma unroll
        for (int nt = 0; nt < 8; ++nt) {
            int col = nt * 16 + colb;
            Po[(size_t)row * 128 + col] = (ushort)f2b(acc[nt][r] + bias[col]);
        }
    }
}

// ---------------- fused edge kernel (natural order, coalesced epilogue) ----------------
__global__ __launch_bounds__(256) void edge_kernel(
    const float* __restrict__ edge_feats,  // [NB,NE,128]
    const int* __restrict__ iIdx, const int* __restrict__ jIdx,
    const ushort* __restrict__ Weg,        // [128][128] bf16 (edge gate)
    const float* __restrict__ b_eg,
    const ushort* __restrict__ Psg, const ushort* __restrict__ Pdg,
    ushort* __restrict__ sigOut,           // [NB,NE,128] bf16
    float* __restrict__ yOut)              // [NB,NE,128]
{
    __shared__ ushort Wl[128 * 128];  // 32 KB; reused as fp32 accL[64][128] after MFMA
    const int b = blockIdx.y;
    const int e0 = blockIdx.x * 64;
    const int tid = threadIdx.x;

    stage_W(Weg, Wl, tid);
    __syncthreads();

    const int lane = tid & 63, wv = tid >> 6;
    const int colb = lane & 15, kgrp = lane >> 4;
    const float* Abase = edge_feats + ((size_t)b * NE + e0) * 128;

    short8 afrag[4];
    load_afrag(Abase + (size_t)(wv * 16 + colb) * 128, kgrp, afrag);
    f32x4 acc[8];
    mfma_frags(afrag, Wl, lane, acc);
    __syncthreads();   // all waves done reading Wl

    float* accL = reinterpret_cast<float*>(Wl);  // [64][128] fp32
#pragma unroll
    for (int r = 0; r < 4; ++r) {
        int row = wv * 16 + kgrp * 4 + r;
#pragma unroll
        for (int nt = 0; nt < 8; ++nt) accL[row * 128 + nt * 16 + colb] = acc[nt][r];
    }
    __syncthreads();

    // epilogue: wave wv owns rows wv*16..wv*16+15; lane owns cols 2*lane, 2*lane+1
    const int c2 = lane * 2;
    const float bg0 = b_eg[c2], bg1 = b_eg[c2 + 1];
    const size_t nbase = (size_t)b * NN;
    for (int rr = 0; rr < 16; ++rr) {
        int row = wv * 16 + rr;
        int e = e0 + row;
        int ie = iIdx[e], je = jIdx[e];
        float a0 = accL[row * 128 + c2], a1 = accL[row * 128 + c2 + 1];
        uint sg2 = *reinterpret_cast<const uint*>(Psg + (nbase + ie) * 128 + c2);
        uint dg2 = *reinterpret_cast<const uint*>(Pdg + (nbase + je) * 128 + c2);
        float y0 = a0 + bg0 + b2f((ushort)(sg2 & 0xffff)) + b2f((ushort)(dg2 & 0xffff));
        float y1 = a1 + bg1 + b2f((ushort)(sg2 >> 16)) + b2f((ushort)(dg2 >> 16));
        float s0 = 1.f / (1.f + __expf(-y0));
        float s1 = 1.f / (1.f + __expf(-y1));
        f32x2 efv = *reinterpret_cast<const f32x2*>(Abase + (size_t)row * 128 + c2);
        f32x2 yv;
        yv[0] = efv[0] + y0 * s0;
        yv[1] = efv[1] + y1 * s1;
        *reinterpret_cast<f32x2*>(yOut + ((size_t)b * NE + e) * 128 + c2) = yv;
        uint spack = (uint)(ushort)f2b(s0) | ((uint)(ushort)f2b(s1) << 16);
        *reinterpret_cast<uint*>(sigOut + ((size_t)b * NE + e) * 128 + c2) = spack;
    }
}

// ---------------- per-node CSR reduce + finalize ----------------
__global__ __launch_bounds__(256) void node_reduce_kernel(
    const ushort* __restrict__ sigma,   // [NB,NE,128] bf16
    const int* __restrict__ perm,       // [NE]
    const int* __restrict__ start,      // [NN+1]
    const int* __restrict__ jIdx,       // [NE]
    const ushort* __restrict__ Pdu,     // [MROWS,128] bf16
    const ushort* __restrict__ Psu,     // [MROWS,128] bf16
    const float* __restrict__ nf,       // [MROWS,128]
    float* __restrict__ xOut)           // [MROWS,128]
{
    int task = blockIdx.x * 4 + (threadIdx.x >> 6);  // 0..16383
    int lane = threadIdx.x & 63;
    int b = task >> 12;
    int n = task & 4095;
    int s0 = start[n], s1 = start[n + 1];

    const size_t ebase = (size_t)b * NE;
    const size_t nbase = (size_t)b * NN;

    float S0 = 0.f, S1 = 0.f, Sh0 = 0.f, Sh1 = 0.f;
    for (int k = s0; k < s1; ++k) {
        int e = perm[k];
        int j = jIdx[e];
        uint sg2 = *reinterpret_cast<const uint*>(sigma + (ebase + e) * 128 + lane * 2);
        uint du2 = *reinterpret_cast<const uint*>(Pdu + (nbase + j) * 128 + lane * 2);
        float sa = b2f((ushort)(sg2 & 0xffff));
        float sb = b2f((ushort)(sg2 >> 16));
        float da = b2f((ushort)(du2 & 0xffff));
        float db = b2f((ushort)(du2 >> 16));
        S0 += sa; S1 += sb;
        Sh0 += da * sa; Sh1 += db * sb;
    }

    size_t off = (nbase + n) * 128 + lane * 2;
    uint su2 = *reinterpret_cast<const uint*>(Psu + off);
    f32x2 a = *reinterpret_cast<const f32x2*>(nf + off);
    float h0 = Sh0 / (S0 + 1e-6f);
    float h1 = Sh1 / (S1 + 1e-6f);
    float v0 = b2f((ushort)(su2 & 0xffff)) + h0;
    float v1 = b2f((ushort)(su2 >> 16)) + h1;
    f32x2 r;
    r[0] = a[0] + v0 / (1.f + __expf(-v0));
    r[1] = a[1] + v1 / (1.f + __expf(-v1));
    *reinterpret_cast<f32x2*>(xOut + off) = r;
}

extern "C" void kernel_launch(void* const* d_in, const int* in_sizes, int n_in,
                              void* d_out, int out_size, void* d_ws, size_t ws_size,
                              hipStream_t stream) {
    (void)in_sizes; (void)n_in; (void)out_size; (void)ws_size;

    const float* node_feats = (const float*)d_in[0];
    const float* edge_feats = (const float*)d_in[1];
    const int* iIdx = (const int*)d_in[2];
    const int* jIdx = (const int*)d_in[3];
    const float* Wsg = (const float*)d_in[4];  const float* bsg = (const float*)d_in[5];
    const float* Wdg = (const float*)d_in[6];  const float* bdg = (const float*)d_in[7];
    const float* Weg = (const float*)d_in[8];  const float* beg = (const float*)d_in[9];
    const float* Wsu = (const float*)d_in[10]; const float* bsu = (const float*)d_in[11];
    const float* Wdu = (const float*)d_in[12]; const float* bdu = (const float*)d_in[13];

    float* out = (float*)d_out;
    float* xOut = out;                               // [NB,NN,128]
    float* yOut = out + (size_t)MROWS * 128;         // [NB,NE,128]

    // workspace layout
    ushort* sigma = (ushort*)d_ws;                            // [NB*NE*128] bf16 (67.1 MB)
    ushort* P = sigma + (size_t)NB * NE * 128;                // [4][MROWS][128] bf16 (16.8 MB)
    ushort* Wbf = P + (size_t)4 * MROWS * 128;                // [5][128][128] bf16 (160 KB)
    int* perm = (int*)(Wbf + 5 * 16384);                      // [NE]
    int* cnt = perm + NE;                                     // [4096]
    int* cur = cnt + 4096;                                    // [4096]
    int* start = cur + 4096;                                  // [4097]

    hipMemsetAsync(cnt, 0, 2 * 4096 * sizeof(int), stream);   // cnt + cur

    prep_weights<<<(5 * 16384) / 256, 256, 0, stream>>>(Wsg, Wdg, Wdu, Wsu, Weg, Wbf);

    hist_kernel<<<NE / 256, 256, 0, stream>>>(iIdx, cnt);
    scan_kernel<<<1, 256, 0, stream>>>(cnt, start);
    scatter_kernel<<<NE / 256, 256, 0, stream>>>(iIdx, start, cur, perm);

    dim3 gA(MROWS / 64, 4);
    node_proj_kernel<<<gA, 256, 0, stream>>>(node_feats, Wbf, bsg, bdg, bdu, bsu, P);

    dim3 gB(NE / 64, NB);
    edge_kernel<<<gB, 256, 0, stream>>>(edge_feats, iIdx, jIdx, Wbf + (size_t)4 * 16384, beg,
                                        P,                                  // src_gate
                                        P + (size_t)1 * MROWS * 128,        // dst_gate
                                        sigma, yOut);

    node_reduce_kernel<<<MROWS / 4, 256, 0, stream>>>(
        sigma, perm, start, jIdx,
        P + (size_t)2 * MROWS * 128,   // dst_update
        P + (size_t)3 * MROWS * 128,   // src_update
        node_feats, xOut);
}

// Round 5
// 191.316 us; speedup vs baseline: 1.4500x; 1.0366x over previous
//
#include <hip/hip_runtime.h>
#include <hip/hip_bf16.h>

typedef __attribute__((ext_vector_type(8))) short short8;
typedef __attribute__((ext_vector_type(4))) float f32x4;
typedef __attribute__((ext_vector_type(2))) float f32x2;

#define DEVI __device__ __forceinline__

static constexpr int NB = 4;
static constexpr int NN = 4096;
static constexpr int NE = 65536;
static constexpr int MROWS = NB * NN; // 16384
static constexpr int TILES = 4;       // 64-edge tiles per block in edge_kernel

DEVI short f2b(float f) {
    __hip_bfloat16 h = __float2bfloat16(f);
    return *reinterpret_cast<short*>(&h);
}
DEVI float b2f(ushort u) {
    uint v = (uint)u << 16;
    float f;
    __builtin_memcpy(&f, &v, 4);
    return f;
}

// ---------------- prep: fp32 -> bf16 weights ----------------
// order: [0]=W_src_gate [1]=W_dst_gate [2]=W_dst_update [3]=W_src_update [4]=W_edge_gate
__global__ void prep_weights(const float* __restrict__ w0, const float* __restrict__ w1,
                             const float* __restrict__ w2, const float* __restrict__ w3,
                             const float* __restrict__ w4, ushort* __restrict__ out) {
    int idx = blockIdx.x * 256 + threadIdx.x;   // 5*16384 total
    int wsel = idx >> 14;
    int off = idx & 16383;
    const float* src = wsel == 0 ? w0 : wsel == 1 ? w1 : wsel == 2 ? w2 : wsel == 3 ? w3 : w4;
    out[idx] = (ushort)f2b(src[off]);
}

// ---------------- counting sort of edges by destination i ----------------
__global__ void hist_kernel(const int* __restrict__ iIdx, int* __restrict__ cnt) {
    int e = blockIdx.x * 256 + threadIdx.x;
    atomicAdd(&cnt[iIdx[e]], 1);
}

__global__ __launch_bounds__(256) void scan_kernel(const int* __restrict__ cnt,
                                                   int* __restrict__ start) {
    __shared__ int ls[256];
    int t = threadIdx.x;
    int base = t * 16;
    int loc[16];
    int s = 0;
#pragma unroll
    for (int q = 0; q < 16; ++q) { loc[q] = s; s += cnt[base + q]; }
    ls[t] = s;
    __syncthreads();
    for (int off = 1; off < 256; off <<= 1) {
        int v = (t >= off) ? ls[t - off] : 0;
        __syncthreads();
        ls[t] += v;
        __syncthreads();
    }
    int ex = ls[t] - s;   // exclusive prefix of this thread's chunk
#pragma unroll
    for (int q = 0; q < 16; ++q) start[base + q] = ex + loc[q];
    if (t == 255) start[4096] = ex + s;
}

// rank[e] = sorted position of edge e; jsort[pos] = jIdx[e]
__global__ void scatter_kernel(const int* __restrict__ iIdx, const int* __restrict__ jIdx,
                               const int* __restrict__ start, int* __restrict__ cur,
                               int* __restrict__ rank, int* __restrict__ jsort) {
    int e = blockIdx.x * 256 + threadIdx.x;
    int iv = iIdx[e];
    int pos = start[iv] + atomicAdd(&cur[iv], 1);
    rank[e] = pos;
    jsort[pos] = jIdx[e];
}

// Stage one 128x128 bf16 weight into LDS, XOR-swizzled (byte ^= (n&7)<<4).
DEVI void stage_W(const ushort* __restrict__ Wg, ushort* Wl, int tid) {
    int n = tid >> 1;           // row 0..127
    int kh = (tid & 1) * 64;    // half-row in bf16 elems
#pragma unroll
    for (int c = 0; c < 8; ++c) {
        int k = kh + c * 8;
        short8 v = *reinterpret_cast<const short8*>(Wg + n * 128 + k);
        int byt = (n * 256 + k * 2) ^ ((n & 7) << 4);
        *reinterpret_cast<short8*>(reinterpret_cast<char*>(Wl) + byt) = v;
    }
}

// Load this lane's A fragments (K=128 split in 4 ks-slices) from a fp32 row.
DEVI void load_afrag(const float* __restrict__ rowptr, int kgrp, short8 afrag[4]) {
#pragma unroll
    for (int ks = 0; ks < 4; ++ks) {
        int k0 = ks * 32 + kgrp * 8;
        f32x4 lo = *reinterpret_cast<const f32x4*>(rowptr + k0);
        f32x4 hi = *reinterpret_cast<const f32x4*>(rowptr + k0 + 4);
        short8 a;
#pragma unroll
        for (int q = 0; q < 4; ++q) a[q] = f2b(lo[q]);
#pragma unroll
        for (int q = 0; q < 4; ++q) a[4 + q] = f2b(hi[q]);
        afrag[ks] = a;
    }
}

// acc[nt]: row = wv*16 + (lane>>4)*4 + r, col = nt*16 + (lane&15), for this wave's 16-row tile.
DEVI void mfma_frags(const short8 afrag[4], const ushort* __restrict__ Wl,
                     int lane, f32x4 acc[8]) {
    const int colb = lane & 15;
    const int kgrp = lane >> 4;
#pragma unroll
    for (int nt = 0; nt < 8; ++nt) acc[nt] = f32x4{0.f, 0.f, 0.f, 0.f};
#pragma unroll
    for (int ks = 0; ks < 4; ++ks) {
#pragma unroll
        for (int nt = 0; nt < 8; ++nt) {
            int n = nt * 16 + colb;
            int byt = (n * 256 + (ks * 32 + kgrp * 8) * 2) ^ ((n & 7) << 4);
            short8 bfrag = *reinterpret_cast<const short8*>(
                reinterpret_cast<const char*>(Wl) + byt);
            acc[nt] = __builtin_amdgcn_mfma_f32_16x16x32_bf16(afrag[ks], bfrag, acc[nt], 0, 0, 0);
        }
    }
}

// ---------------- node projections: P[w] = bf16(node_feats @ W[w]^T + b[w]) ----------------
__global__ __launch_bounds__(256) void node_proj_kernel(
    const float* __restrict__ node_feats,  // [MROWS,128]
    const ushort* __restrict__ Wbf,        // [5][128][128] bf16
    const float* __restrict__ bias0, const float* __restrict__ bias1,
    const float* __restrict__ bias2, const float* __restrict__ bias3,
    ushort* __restrict__ P)                // [4][MROWS][128] bf16
{
    __shared__ ushort Wl[128 * 128];  // 32 KB
    const int widx = blockIdx.y;
    const int row0 = blockIdx.x * 64;
    const int tid = threadIdx.x;

    stage_W(Wbf + (size_t)widx * 16384, Wl, tid);
    __syncthreads();

    const int lane = tid & 63, wv = tid >> 6;
    const int colb = lane & 15, kgrp = lane >> 4;
    short8 afrag[4];
    load_afrag(node_feats + (size_t)(row0 + wv * 16 + colb) * 128, kgrp, afrag);
    f32x4 acc[8];
    mfma_frags(afrag, Wl, lane, acc);

    const float* bias = widx == 0 ? bias0 : widx == 1 ? bias1 : widx == 2 ? bias2 : bias3;
    ushort* Po = P + (size_t)widx * MROWS * 128;
#pragma unroll
    for (int r = 0; r < 4; ++r) {
        int row = row0 + wv * 16 + kgrp * 4 + r;
#pragma unroll
        for (int nt = 0; nt < 8; ++nt) {
            int col = nt * 16 + colb;
            Po[(size_t)row * 128 + col] = (ushort)f2b(acc[nt][r] + bias[col]);
        }
    }
}

// ---------------- fused edge kernel: tile loop, W staged once, no in-loop barriers ----------------
__global__ __launch_bounds__(256) void edge_kernel(
    const float* __restrict__ edge_feats,  // [NB,NE,128]
    const int* __restrict__ iIdx, const int* __restrict__ jIdx,
    const int* __restrict__ rank,          // [NE] sorted position of edge e
    const ushort* __restrict__ Weg,        // [128][128] bf16 (edge gate)
    const float* __restrict__ b_eg,
    const ushort* __restrict__ Psg, const ushort* __restrict__ Pdg,
    ushort* __restrict__ sigS,             // [NB,NE,128] bf16, SORTED edge order
    float* __restrict__ yOut)              // [NB,NE,128]
{
    __shared__ ushort Wl[128 * 128];  // 32 KB, read-only after stage
    const int b = blockIdx.y;
    const int tid = threadIdx.x;

    stage_W(Weg, Wl, tid);
    __syncthreads();

    const int lane = tid & 63, wv = tid >> 6;
    const int colb = lane & 15, kgrp = lane >> 4;
    const float* Ab = edge_feats + (size_t)b * NE * 128;
    const size_t nbase = (size_t)b * NN;

    // hoist bias for this lane's 8 columns
    float bg[8];
#pragma unroll
    for (int nt = 0; nt < 8; ++nt) bg[nt] = b_eg[nt * 16 + colb];

    for (int t = 0; t < TILES; ++t) {
        const int e0 = (blockIdx.x * TILES + t) * 64;
        short8 afrag[4];
        load_afrag(Ab + (size_t)(e0 + wv * 16 + colb) * 128, kgrp, afrag);
        f32x4 acc[8];
        mfma_frags(afrag, Wl, lane, acc);

        // epilogue in fragment layout (round-2 proven)
#pragma unroll
        for (int r = 0; r < 4; ++r) {
            int erow = wv * 16 + kgrp * 4 + r;
            int e = e0 + erow;
            int ie = iIdx[e], je = jIdx[e], rk = rank[e];
            const ushort* sg = Psg + (nbase + ie) * 128;
            const ushort* dg = Pdg + (nbase + je) * 128;
            const float* ef = Ab + (size_t)e * 128;
            float* yo = yOut + ((size_t)b * NE + e) * 128;
            ushort* so = sigS + ((size_t)b * NE + rk) * 128;
#pragma unroll
            for (int nt = 0; nt < 8; ++nt) {
                int col = nt * 16 + colb;
                float y = acc[nt][r] + bg[nt] + b2f(sg[col]) + b2f(dg[col]);
                float sig = 1.0f / (1.0f + __expf(-y));
                yo[col] = ef[col] + y * sig;   // edge residual + silu(y)
                so[col] = (ushort)f2b(sig);
            }
        }
    }
}

// ---------------- per-node streaming reduce + finalize ----------------
__global__ __launch_bounds__(256) void node_reduce_kernel(
    const ushort* __restrict__ sigS,    // [NB,NE,128] bf16, sorted edge order
    const int* __restrict__ start,      // [NN+1]
    const int* __restrict__ jsort,      // [NE]
    const ushort* __restrict__ Pdu,     // [MROWS,128] bf16
    const ushort* __restrict__ Psu,     // [MROWS,128] bf16
    const float* __restrict__ nf,       // [MROWS,128]
    float* __restrict__ xOut)           // [MROWS,128]
{
    int task = blockIdx.x * 4 + (threadIdx.x >> 6);  // 0..16383
    int lane = threadIdx.x & 63;
    int b = task >> 12;
    int n = task & 4095;
    int s0 = start[n], s1 = start[n + 1];

    const size_t ebase = (size_t)b * NE;
    const size_t nbase = (size_t)b * NN;

    float S0 = 0.f, S1 = 0.f, Sh0 = 0.f, Sh1 = 0.f;
    for (int k = s0; k < s1; ++k) {
        int j = jsort[k];
        uint sg2 = *reinterpret_cast<const uint*>(sigS + (ebase + k) * 128 + lane * 2);
        uint du2 = *reinterpret_cast<const uint*>(Pdu + (nbase + j) * 128 + lane * 2);
        float sa = b2f((ushort)(sg2 & 0xffff));
        float sb = b2f((ushort)(sg2 >> 16));
        float da = b2f((ushort)(du2 & 0xffff));
        float db = b2f((ushort)(du2 >> 16));
        S0 += sa; S1 += sb;
        Sh0 += da * sa; Sh1 += db * sb;
    }

    size_t off = (nbase + n) * 128 + lane * 2;
    uint su2 = *reinterpret_cast<const uint*>(Psu + off);
    f32x2 a = *reinterpret_cast<const f32x2*>(nf + off);
    float h0 = Sh0 / (S0 + 1e-6f);
    float h1 = Sh1 / (S1 + 1e-6f);
    float v0 = b2f((ushort)(su2 & 0xffff)) + h0;
    float v1 = b2f((ushort)(su2 >> 16)) + h1;
    f32x2 r;
    r[0] = a[0] + v0 / (1.f + __expf(-v0));
    r[1] = a[1] + v1 / (1.f + __expf(-v1));
    *reinterpret_cast<f32x2*>(xOut + off) = r;
}

extern "C" void kernel_launch(void* const* d_in, const int* in_sizes, int n_in,
                              void* d_out, int out_size, void* d_ws, size_t ws_size,
                              hipStream_t stream) {
    (void)in_sizes; (void)n_in; (void)out_size; (void)ws_size;

    const float* node_feats = (const float*)d_in[0];
    const float* edge_feats = (const float*)d_in[1];
    const int* iIdx = (const int*)d_in[2];
    const int* jIdx = (const int*)d_in[3];
    const float* Wsg = (const float*)d_in[4];  const float* bsg = (const float*)d_in[5];
    const float* Wdg = (const float*)d_in[6];  const float* bdg = (const float*)d_in[7];
    const float* Weg = (const float*)d_in[8];  const float* beg = (const float*)d_in[9];
    const float* Wsu = (const float*)d_in[10]; const float* bsu = (const float*)d_in[11];
    const float* Wdu = (const float*)d_in[12]; const float* bdu = (const float*)d_in[13];

    float* out = (float*)d_out;
    float* xOut = out;                               // [NB,NN,128]
    float* yOut = out + (size_t)MROWS * 128;         // [NB,NE,128]

    // workspace layout
    ushort* sigS = (ushort*)d_ws;                             // [NB*NE*128] bf16 (67.1 MB)
    ushort* P = sigS + (size_t)NB * NE * 128;                 // [4][MROWS][128] bf16 (16.8 MB)
    ushort* Wbf = P + (size_t)4 * MROWS * 128;                // [5][128][128] bf16 (160 KB)
    int* rank = (int*)(Wbf + 5 * 16384);                      // [NE]
    int* jsort = rank + NE;                                   // [NE]
    int* cnt = jsort + NE;                                    // [4096]
    int* cur = cnt + 4096;                                    // [4096]
    int* start = cur + 4096;                                  // [4097]

    hipMemsetAsync(cnt, 0, 2 * 4096 * sizeof(int), stream);   // cnt + cur

    prep_weights<<<(5 * 16384) / 256, 256, 0, stream>>>(Wsg, Wdg, Wdu, Wsu, Weg, Wbf);

    hist_kernel<<<NE / 256, 256, 0, stream>>>(iIdx, cnt);
    scan_kernel<<<1, 256, 0, stream>>>(cnt, start);
    scatter_kernel<<<NE / 256, 256, 0, stream>>>(iIdx, jIdx, start, cur, rank, jsort);

    dim3 gA(MROWS / 64, 4);
    node_proj_kernel<<<gA, 256, 0, stream>>>(node_feats, Wbf, bsg, bdg, bdu, bsu, P);

    dim3 gB(NE / (64 * TILES), NB);
    edge_kernel<<<gB, 256, 0, stream>>>(edge_feats, iIdx, jIdx, rank,
                                        Wbf + (size_t)4 * 16384, beg,
                                        P,                                  // src_gate
                                        P + (size_t)1 * MROWS * 128,        // dst_gate
                                        sigS, yOut);

    node_reduce_kernel<<<MROWS / 4, 256, 0, stream>>>(
        sigS, start, jsort,
        P + (size_t)2 * MROWS * 128,   // dst_update
        P + (size_t)3 * MROWS * 128,   // src_update
        node_feats, xOut);
}

// Round 6
// 168.299 us; speedup vs baseline: 1.6482x; 1.1368x over previous
//
#include <hip/hip_runtime.h>
#include <hip/hip_bf16.h>

typedef __attribute__((ext_vector_type(8))) short short8;
typedef __attribute__((ext_vector_type(4))) float f32x4;
typedef __attribute__((ext_vector_type(2))) float f32x2;

#define DEVI __device__ __forceinline__

static constexpr int NB = 4;
static constexpr int NN = 4096;
static constexpr int NE = 65536;
static constexpr int MROWS = NB * NN; // 16384

DEVI short f2b(float f) {
    __hip_bfloat16 h = __float2bfloat16(f);
    return *reinterpret_cast<short*>(&h);
}
DEVI float b2f(ushort u) {
    uint v = (uint)u << 16;
    float f;
    __builtin_memcpy(&f, &v, 4);
    return f;
}

// ---------------- prep: fp32 -> bf16 weights ----------------
// order: [0]=W_src_gate [1]=W_dst_gate [2]=W_dst_update [3]=W_src_update [4]=W_edge_gate
__global__ void prep_weights(const float* __restrict__ w0, const float* __restrict__ w1,
                             const float* __restrict__ w2, const float* __restrict__ w3,
                             const float* __restrict__ w4, ushort* __restrict__ out) {
    int idx = blockIdx.x * 256 + threadIdx.x;   // 5*16384 total
    int wsel = idx >> 14;
    int off = idx & 16383;
    const float* src = wsel == 0 ? w0 : wsel == 1 ? w1 : wsel == 2 ? w2 : wsel == 3 ? w3 : w4;
    out[idx] = (ushort)f2b(src[off]);
}

// ---------------- counting sort of edges by destination i ----------------
__global__ void hist_kernel(const int* __restrict__ iIdx, int* __restrict__ cnt) {
    int e = blockIdx.x * 256 + threadIdx.x;
    atomicAdd(&cnt[iIdx[e]], 1);
}

__global__ __launch_bounds__(256) void scan_kernel(const int* __restrict__ cnt,
                                                   int* __restrict__ start) {
    __shared__ int ls[256];
    int t = threadIdx.x;
    int base = t * 16;
    int loc[16];
    int s = 0;
#pragma unroll
    for (int q = 0; q < 16; ++q) { loc[q] = s; s += cnt[base + q]; }
    ls[t] = s;
    __syncthreads();
    for (int off = 1; off < 256; off <<= 1) {
        int v = (t >= off) ? ls[t - off] : 0;
        __syncthreads();
        ls[t] += v;
        __syncthreads();
    }
    int ex = ls[t] - s;   // exclusive prefix of this thread's chunk
#pragma unroll
    for (int q = 0; q < 16; ++q) start[base + q] = ex + loc[q];
    if (t == 255) start[4096] = ex + s;
}

// rank[e] = sorted position of edge e; jsort[pos] = jIdx[e]
__global__ void scatter_kernel(const int* __restrict__ iIdx, const int* __restrict__ jIdx,
                               const int* __restrict__ start, int* __restrict__ cur,
                               int* __restrict__ rank, int* __restrict__ jsort) {
    int e = blockIdx.x * 256 + threadIdx.x;
    int iv = iIdx[e];
    int pos = start[iv] + atomicAdd(&cur[iv], 1);
    rank[e] = pos;
    jsort[pos] = jIdx[e];
}

// Stage one 128x128 bf16 weight into LDS, XOR-swizzled (byte ^= (n&7)<<4). 256 threads.
DEVI void stage_W256(const ushort* __restrict__ Wg, ushort* Wl, int tid) {
    int n = tid >> 1;           // row 0..127
    int kh = (tid & 1) * 64;    // half-row in bf16 elems
#pragma unroll
    for (int c = 0; c < 8; ++c) {
        int k = kh + c * 8;
        short8 v = *reinterpret_cast<const short8*>(Wg + n * 128 + k);
        int byt = (n * 256 + k * 2) ^ ((n & 7) << 4);
        *reinterpret_cast<short8*>(reinterpret_cast<char*>(Wl) + byt) = v;
    }
}

// Same staging with 512 threads.
DEVI void stage_W512(const ushort* __restrict__ Wg, ushort* Wl, int tid) {
    int n = tid >> 2;           // row 0..127
    int kq = (tid & 3) * 32;    // quarter-row in bf16 elems
#pragma unroll
    for (int c = 0; c < 4; ++c) {
        int k = kq + c * 8;
        short8 v = *reinterpret_cast<const short8*>(Wg + n * 128 + k);
        int byt = (n * 256 + k * 2) ^ ((n & 7) << 4);
        *reinterpret_cast<short8*>(reinterpret_cast<char*>(Wl) + byt) = v;
    }
}

// Load this lane's A fragments (K=128 split in 4 ks-slices) from a fp32 row.
DEVI void load_afrag(const float* __restrict__ rowptr, int kgrp, short8 afrag[4]) {
#pragma unroll
    for (int ks = 0; ks < 4; ++ks) {
        int k0 = ks * 32 + kgrp * 8;
        f32x4 lo = *reinterpret_cast<const f32x4*>(rowptr + k0);
        f32x4 hi = *reinterpret_cast<const f32x4*>(rowptr + k0 + 4);
        short8 a;
#pragma unroll
        for (int q = 0; q < 4; ++q) a[q] = f2b(lo[q]);
#pragma unroll
        for (int q = 0; q < 4; ++q) a[4 + q] = f2b(hi[q]);
        afrag[ks] = a;
    }
}

// acc[nt]: row = wv*16 + (lane>>4)*4 + r, col = nt*16 + (lane&15), for this wave's 16-row tile.
DEVI void mfma_frags(const short8 afrag[4], const ushort* __restrict__ Wl,
                     int lane, f32x4 acc[8]) {
    const int colb = lane & 15;
    const int kgrp = lane >> 4;
#pragma unroll
    for (int nt = 0; nt < 8; ++nt) acc[nt] = f32x4{0.f, 0.f, 0.f, 0.f};
#pragma unroll
    for (int ks = 0; ks < 4; ++ks) {
#pragma unroll
        for (int nt = 0; nt < 8; ++nt) {
            int n = nt * 16 + colb;
            int byt = (n * 256 + (ks * 32 + kgrp * 8) * 2) ^ ((n & 7) << 4);
            short8 bfrag = *reinterpret_cast<const short8*>(
                reinterpret_cast<const char*>(Wl) + byt);
            acc[nt] = __builtin_amdgcn_mfma_f32_16x16x32_bf16(afrag[ks], bfrag, acc[nt], 0, 0, 0);
        }
    }
}

// ---------------- node projections: P[w] = bf16(node_feats @ W[w]^T + b[w]) ----------------
__global__ __launch_bounds__(256) void node_proj_kernel(
    const float* __restrict__ node_feats,  // [MROWS,128]
    const ushort* __restrict__ Wbf,        // [5][128][128] bf16
    const float* __restrict__ bias0, const float* __restrict__ bias1,
    const float* __restrict__ bias2, const float* __restrict__ bias3,
    ushort* __restrict__ P)                // [4][MROWS][128] bf16
{
    __shared__ ushort Wl[128 * 128];  // 32 KB
    const int widx = blockIdx.y;
    const int row0 = blockIdx.x * 64;
    const int tid = threadIdx.x;

    stage_W256(Wbf + (size_t)widx * 16384, Wl, tid);
    __syncthreads();

    const int lane = tid & 63, wv = tid >> 6;
    const int colb = lane & 15, kgrp = lane >> 4;
    short8 afrag[4];
    load_afrag(node_feats + (size_t)(row0 + wv * 16 + colb) * 128, kgrp, afrag);
    f32x4 acc[8];
    mfma_frags(afrag, Wl, lane, acc);

    const float* bias = widx == 0 ? bias0 : widx == 1 ? bias1 : widx == 2 ? bias2 : bias3;
    ushort* Po = P + (size_t)widx * MROWS * 128;
#pragma unroll
    for (int r = 0; r < 4; ++r) {
        int row = row0 + wv * 16 + kgrp * 4 + r;
#pragma unroll
        for (int nt = 0; nt < 8; ++nt) {
            int col = nt * 16 + colb;
            Po[(size_t)row * 128 + col] = (ushort)f2b(acc[nt][r] + bias[col]);
        }
    }
}

// ---------------- fused edge kernel: 8 waves share one W stage, single tile per wave ----------------
__global__ __launch_bounds__(512, 4) void edge_kernel(
    const float* __restrict__ edge_feats,  // [NB,NE,128]
    const int* __restrict__ iIdx, const int* __restrict__ jIdx,
    const int* __restrict__ rank,          // [NE] sorted position of edge e
    const ushort* __restrict__ Weg,        // [128][128] bf16 (edge gate)
    const float* __restrict__ b_eg,
    const ushort* __restrict__ Psg, const ushort* __restrict__ Pdg,
    ushort* __restrict__ sigS,             // [NB,NE,128] bf16, SORTED edge order
    float* __restrict__ yOut)              // [NB,NE,128]
{
    __shared__ ushort Wl[128 * 128];  // 32 KB, read-only after stage
    const int b = blockIdx.y;
    const int e0 = blockIdx.x * 128;
    const int tid = threadIdx.x;

    stage_W512(Weg, Wl, tid);
    __syncthreads();

    const int lane = tid & 63, wv = tid >> 6;   // wv 0..7
    const int colb = lane & 15, kgrp = lane >> 4;
    const float* Ab = edge_feats + (size_t)b * NE * 128;
    const size_t nbase = (size_t)b * NN;

    short8 afrag[4];
    load_afrag(Ab + (size_t)(e0 + wv * 16 + colb) * 128, kgrp, afrag);
    f32x4 acc[8];
    mfma_frags(afrag, Wl, lane, acc);

    // epilogue in fragment layout (round-2/5 proven)
#pragma unroll
    for (int r = 0; r < 4; ++r) {
        int erow = wv * 16 + kgrp * 4 + r;
        int e = e0 + erow;
        int ie = iIdx[e], je = jIdx[e], rk = rank[e];
        const ushort* sg = Psg + (nbase + ie) * 128;
        const ushort* dg = Pdg + (nbase + je) * 128;
        const float* ef = Ab + (size_t)(e0 + erow) * 128;
        float* yo = yOut + ((size_t)b * NE + e) * 128;
        ushort* so = sigS + ((size_t)b * NE + rk) * 128;
#pragma unroll
        for (int nt = 0; nt < 8; ++nt) {
            int col = nt * 16 + colb;
            float y = acc[nt][r] + b_eg[col] + b2f(sg[col]) + b2f(dg[col]);
            float sig = 1.0f / (1.0f + __expf(-y));
            yo[col] = ef[col] + y * sig;   // edge residual + silu(y)
            so[col] = (ushort)f2b(sig);
        }
    }
}

// ---------------- per-node streaming reduce + finalize (2-way unrolled) ----------------
__global__ __launch_bounds__(256) void node_reduce_kernel(
    const ushort* __restrict__ sigS,    // [NB,NE,128] bf16, sorted edge order
    const int* __restrict__ start,      // [NN+1]
    const int* __restrict__ jsort,      // [NE]
    const ushort* __restrict__ Pdu,     // [MROWS,128] bf16
    const ushort* __restrict__ Psu,     // [MROWS,128] bf16
    const float* __restrict__ nf,       // [MROWS,128]
    float* __restrict__ xOut)           // [MROWS,128]
{
    int task = blockIdx.x * 4 + (threadIdx.x >> 6);  // 0..16383
    int lane = threadIdx.x & 63;
    int b = task >> 12;
    int n = task & 4095;
    int s0 = start[n], s1 = start[n + 1];

    const size_t ebase = (size_t)b * NE;
    const size_t nbase = (size_t)b * NN;

    float S0 = 0.f, S1 = 0.f, Sh0 = 0.f, Sh1 = 0.f;
    int k = s0;
    for (; k + 2 <= s1; k += 2) {
        int ja = jsort[k], jb = jsort[k + 1];
        uint sa2 = *reinterpret_cast<const uint*>(sigS + (ebase + k) * 128 + lane * 2);
        uint sb2 = *reinterpret_cast<const uint*>(sigS + (ebase + k + 1) * 128 + lane * 2);
        uint da2 = *reinterpret_cast<const uint*>(Pdu + (nbase + ja) * 128 + lane * 2);
        uint db2 = *reinterpret_cast<const uint*>(Pdu + (nbase + jb) * 128 + lane * 2);
        float sa0 = b2f((ushort)(sa2 & 0xffff)), sa1 = b2f((ushort)(sa2 >> 16));
        float sb0 = b2f((ushort)(sb2 & 0xffff)), sb1 = b2f((ushort)(sb2 >> 16));
        float da0 = b2f((ushort)(da2 & 0xffff)), da1 = b2f((ushort)(da2 >> 16));
        float db0 = b2f((ushort)(db2 & 0xffff)), db1 = b2f((ushort)(db2 >> 16));
        S0 += sa0 + sb0; S1 += sa1 + sb1;
        Sh0 += da0 * sa0 + db0 * sb0;
        Sh1 += da1 * sa1 + db1 * sb1;
    }
    if (k < s1) {
        int j = jsort[k];
        uint sg2 = *reinterpret_cast<const uint*>(sigS + (ebase + k) * 128 + lane * 2);
        uint du2 = *reinterpret_cast<const uint*>(Pdu + (nbase + j) * 128 + lane * 2);
        float sa = b2f((ushort)(sg2 & 0xffff)), sb = b2f((ushort)(sg2 >> 16));
        float da = b2f((ushort)(du2 & 0xffff)), db = b2f((ushort)(du2 >> 16));
        S0 += sa; S1 += sb;
        Sh0 += da * sa; Sh1 += db * sb;
    }

    size_t off = (nbase + n) * 128 + lane * 2;
    uint su2 = *reinterpret_cast<const uint*>(Psu + off);
    f32x2 a = *reinterpret_cast<const f32x2*>(nf + off);
    float h0 = Sh0 / (S0 + 1e-6f);
    float h1 = Sh1 / (S1 + 1e-6f);
    float v0 = b2f((ushort)(su2 & 0xffff)) + h0;
    float v1 = b2f((ushort)(su2 >> 16)) + h1;
    f32x2 r;
    r[0] = a[0] + v0 / (1.f + __expf(-v0));
    r[1] = a[1] + v1 / (1.f + __expf(-v1));
    *reinterpret_cast<f32x2*>(xOut + off) = r;
}

extern "C" void kernel_launch(void* const* d_in, const int* in_sizes, int n_in,
                              void* d_out, int out_size, void* d_ws, size_t ws_size,
                              hipStream_t stream) {
    (void)in_sizes; (void)n_in; (void)out_size; (void)ws_size;

    const float* node_feats = (const float*)d_in[0];
    const float* edge_feats = (const float*)d_in[1];
    const int* iIdx = (const int*)d_in[2];
    const int* jIdx = (const int*)d_in[3];
    const float* Wsg = (const float*)d_in[4];  const float* bsg = (const float*)d_in[5];
    const float* Wdg = (const float*)d_in[6];  const float* bdg = (const float*)d_in[7];
    const float* Weg = (const float*)d_in[8];  const float* beg = (const float*)d_in[9];
    const float* Wsu = (const float*)d_in[10]; const float* bsu = (const float*)d_in[11];
    const float* Wdu = (const float*)d_in[12]; const float* bdu = (const float*)d_in[13];

    float* out = (float*)d_out;
    float* xOut = out;                               // [NB,NN,128]
    float* yOut = out + (size_t)MROWS * 128;         // [NB,NE,128]

    // workspace layout
    ushort* sigS = (ushort*)d_ws;                             // [NB*NE*128] bf16 (67.1 MB)
    ushort* P = sigS + (size_t)NB * NE * 128;                 // [4][MROWS][128] bf16 (16.8 MB)
    ushort* Wbf = P + (size_t)4 * MROWS * 128;                // [5][128][128] bf16 (160 KB)
    int* rank = (int*)(Wbf + 5 * 16384);                      // [NE]
    int* jsort = rank + NE;                                   // [NE]
    int* cnt = jsort + NE;                                    // [4096]
    int* cur = cnt + 4096;                                    // [4096]
    int* start = cur + 4096;                                  // [4097]

    hipMemsetAsync(cnt, 0, 2 * 4096 * sizeof(int), stream);   // cnt + cur

    prep_weights<<<(5 * 16384) / 256, 256, 0, stream>>>(Wsg, Wdg, Wdu, Wsu, Weg, Wbf);

    hist_kernel<<<NE / 256, 256, 0, stream>>>(iIdx, cnt);
    scan_kernel<<<1, 256, 0, stream>>>(cnt, start);
    scatter_kernel<<<NE / 256, 256, 0, stream>>>(iIdx, jIdx, start, cur, rank, jsort);

    dim3 gA(MROWS / 64, 4);
    node_proj_kernel<<<gA, 256, 0, stream>>>(node_feats, Wbf, bsg, bdg, bdu, bsu, P);

    dim3 gB(NE / 128, NB);
    edge_kernel<<<gB, 512, 0, stream>>>(edge_feats, iIdx, jIdx, rank,
                                        Wbf + (size_t)4 * 16384, beg,
                                        P,                                  // src_gate
                                        P + (size_t)1 * MROWS * 128,        // dst_gate
                                        sigS, yOut);

    node_reduce_kernel<<<MROWS / 4, 256, 0, stream>>>(
        sigS, start, jsort,
        P + (size_t)2 * MROWS * 128,   // dst_update
        P + (size_t)3 * MROWS * 128,   // src_update
        node_feats, xOut);
}